// Round 1
// baseline (4023.759 us; speedup 1.0000x reference)
//
#include <hip/hip_runtime.h>
#include <cstdint>
#include <cstddef>

// Problem constants
#define D_DIM 256
#define E_DIM 512
#define S_DIM 128
#define B_DIM 1024
#define T_SEQ 133
#define N_UV 1152                 // 2E + S
#define NTOK (B_DIM * T_SEQ)      // 136192
#define CB 64                     // batches per chunk
#define MROWS (CB * T_SEQ)        // 8512 = 133*64 (multiple of 64!)
#define EPSF 1e-5f
#define RSQRT_S 0.08838834764831845f  // 1/sqrt(128)

// ---------------------------------------------------------------------------
// K0: per-token RMS scale: scale[t] = g / max(||x_t|| / 16, eps)
// one wave (64 lanes) per token; lane loads float4 (64*4 = 256 = D)
// ---------------------------------------------------------------------------
__global__ __launch_bounds__(256) void k_rms(const float* __restrict__ x,
                                             const float* __restrict__ g,
                                             float* __restrict__ scale) {
    int wid  = (blockIdx.x << 2) | (threadIdx.x >> 6);
    int lane = threadIdx.x & 63;
    if (wid >= NTOK) return;
    float4 vv = ((const float4*)(x + (size_t)wid * D_DIM))[lane];
    float s = vv.x * vv.x + vv.y * vv.y + vv.z * vv.z + vv.w * vv.w;
#pragma unroll
    for (int off = 32; off > 0; off >>= 1) s += __shfl_down(s, off, 64);
    if (lane == 0) {
        float norm = sqrtf(s) * 0.0625f;  // * D^-0.5 = /16
        scale[wid] = g[0] / fmaxf(norm, EPSF);
    }
}

// ---------------------------------------------------------------------------
// K1: uv = silu( (x*scale) @ Wuv^T ), scatter into u / v / (q,k affine)
// Tiled f32 GEMM, 64x64 tile, BK=16, 256 threads, 4x4 per thread.
// LDS tiles stored transposed [k][m] so inner loop uses ds_read_b128.
// ---------------------------------------------------------------------------
__global__ __launch_bounds__(256) void k_gemm1(
    const float* __restrict__ x,      // [MROWS, D] (chunk base)
    const float* __restrict__ scale,  // [MROWS]
    const float* __restrict__ Wuv,    // [N_UV, D]
    const float* __restrict__ gamma,  // [2*S]
    const float* __restrict__ beta,   // [2*S]
    float* __restrict__ u,            // [MROWS, E]
    float* __restrict__ v,            // [MROWS, E]
    float* __restrict__ qo,           // [MROWS, S]
    float* __restrict__ ko) {         // [MROWS, S]
    __shared__ float As[16][68];      // [k][m], pad 68 -> 16B aligned rows
    __shared__ float Bs[16][68];
    const int tid  = threadIdx.x;
    const int row0 = blockIdx.x * 64;
    const int col0 = blockIdx.y * 64;
    const int tx = tid & 15, ty = tid >> 4;
    const int lr = tid >> 2, ls = tid & 3;
    float acc[4][4] = {};
    const float scA = scale[row0 + lr];
    const float* aptr = x   + (size_t)(row0 + lr) * D_DIM + ls * 4;
    const float* bptr = Wuv + (size_t)(col0 + lr) * D_DIM + ls * 4;

    for (int k0 = 0; k0 < D_DIM; k0 += 16) {
        float4 a4 = *(const float4*)(aptr + k0);
        float4 b4 = *(const float4*)(bptr + k0);
        As[ls * 4 + 0][lr] = a4.x * scA;
        As[ls * 4 + 1][lr] = a4.y * scA;
        As[ls * 4 + 2][lr] = a4.z * scA;
        As[ls * 4 + 3][lr] = a4.w * scA;
        Bs[ls * 4 + 0][lr] = b4.x;
        Bs[ls * 4 + 1][lr] = b4.y;
        Bs[ls * 4 + 2][lr] = b4.z;
        Bs[ls * 4 + 3][lr] = b4.w;
        __syncthreads();
#pragma unroll
        for (int kk2 = 0; kk2 < 16; ++kk2) {
            float4 av = *(const float4*)&As[kk2][ty * 4];
            float4 bv = *(const float4*)&Bs[kk2][tx * 4];
            float aa[4] = {av.x, av.y, av.z, av.w};
            float bb[4] = {bv.x, bv.y, bv.z, bv.w};
#pragma unroll
            for (int i = 0; i < 4; ++i)
#pragma unroll
                for (int j = 0; j < 4; ++j)
                    acc[i][j] = fmaf(aa[i], bb[j], acc[i][j]);
        }
        __syncthreads();
    }

    const int c0 = col0 + tx * 4;
#pragma unroll
    for (int i = 0; i < 4; ++i) {
        const size_t r = row0 + ty * 4 + i;
#pragma unroll
        for (int j = 0; j < 4; ++j) {
            float val = acc[i][j];
            val = val / (1.0f + __expf(-val));  // silu
            const int c = c0 + j;
            if (c < E_DIM) {
                u[r * E_DIM + c] = val;
            } else if (c < 2 * E_DIM) {
                v[r * E_DIM + (c - E_DIM)] = val;
            } else {
                const int s2 = c - 2 * E_DIM;
                qo[r * S_DIM + s2] = fmaf(val, gamma[s2],        beta[s2]);
                ko[r * S_DIM + s2] = fmaf(val, gamma[S_DIM + s2], beta[S_DIM + s2]);
            }
        }
    }
}

// ---------------------------------------------------------------------------
// K2: per-batch attention. Block = (row tile of 16 q-rows) x (batch).
// scores = relu(q k^T / sqrt(S))^2 in LDS; attn = scores @ v; h = u*attn
// written in-place over u. LDS rows padded +4 floats to break 512B-stride
// bank aliasing.
// ---------------------------------------------------------------------------
#define SP 132  // padded row stride (floats) for q/k LDS tiles
__global__ __launch_bounds__(256) void k_attn(
    const float* __restrict__ q,   // [CB*T, S]
    const float* __restrict__ kk,  // [CB*T, S]
    const float* __restrict__ v,   // [CB*T, E]
    float* __restrict__ u) {       // [CB*T, E]  in: u, out: h = u*attn
    const int b  = blockIdx.y;
    const int i0 = blockIdx.x * 16;
    const int nrows = (T_SEQ - i0 < 16) ? (T_SEQ - i0) : 16;
    const float* qb = q  + (size_t)b * T_SEQ * S_DIM;
    const float* kb = kk + (size_t)b * T_SEQ * S_DIM;
    const float* vb = v  + (size_t)b * T_SEQ * E_DIM;
    float*       ub = u  + (size_t)b * T_SEQ * E_DIM;

    __shared__ float qs[16 * SP];        // ~8.4 KB
    __shared__ float ks[64 * SP];        // ~33.8 KB
    __shared__ float kern[16][136];      // ~8.7 KB
    const int tid = threadIdx.x;

    // load q rows (float4, padded stride)
    for (int idx = tid; idx < nrows * (S_DIM / 4); idx += 256) {
        int r = idx >> 5, c = idx & 31;
        ((float4*)(qs + r * SP))[c] =
            ((const float4*)(qb + (size_t)(i0 + r) * S_DIM))[c];
    }

    // scores in j-chunks of 64
    for (int j0 = 0; j0 < T_SEQ; j0 += 64) {
        const int jn = (T_SEQ - j0 < 64) ? (T_SEQ - j0) : 64;
        __syncthreads();  // protect ks reuse
        for (int idx = tid; idx < jn * (S_DIM / 4); idx += 256) {
            int r = idx >> 5, c = idx & 31;
            ((float4*)(ks + r * SP))[c] =
                ((const float4*)(kb + (size_t)(j0 + r) * S_DIM))[c];
        }
        __syncthreads();
        for (int idx = tid; idx < nrows * jn; idx += 256) {
            const int i = idx / jn, j = idx - i * jn;
            const float4* q4 = (const float4*)(qs + i * SP);
            const float4* k4 = (const float4*)(ks + j * SP);
            float acc = 0.0f;
#pragma unroll
            for (int d4 = 0; d4 < S_DIM / 4; ++d4) {
                float4 aq = q4[d4];
                float4 ak = k4[d4];
                acc = fmaf(aq.x, ak.x, acc);
                acc = fmaf(aq.y, ak.y, acc);
                acc = fmaf(aq.z, ak.z, acc);
                acc = fmaf(aq.w, ak.w, acc);
            }
            acc *= RSQRT_S;
            acc = fmaxf(acc, 0.0f);
            kern[i][j0 + j] = acc * acc;
        }
    }
    __syncthreads();

    // attn = kern @ v, then h = u * attn (in place)
    const int irow = tid >> 4;          // 0..15
    const int e0   = (tid & 15) * 8;    // 0..120 within 128-wide e-chunk
    for (int ec = 0; ec < E_DIM; ec += 128) {
        float acc[8] = {};
        for (int j = 0; j < T_SEQ; ++j) {
            const float w = kern[irow][j];
            const float* vp = vb + (size_t)j * E_DIM + ec + e0;
            float4 a = *(const float4*)vp;
            float4 b2 = *(const float4*)(vp + 4);
            acc[0] = fmaf(w, a.x,  acc[0]);
            acc[1] = fmaf(w, a.y,  acc[1]);
            acc[2] = fmaf(w, a.z,  acc[2]);
            acc[3] = fmaf(w, a.w,  acc[3]);
            acc[4] = fmaf(w, b2.x, acc[4]);
            acc[5] = fmaf(w, b2.y, acc[5]);
            acc[6] = fmaf(w, b2.z, acc[6]);
            acc[7] = fmaf(w, b2.w, acc[7]);
        }
        if (irow < nrows) {
            float* up = ub + (size_t)(i0 + irow) * E_DIM + ec + e0;
            float4 h0, h1;
            h0.x = up[0] * acc[0]; h0.y = up[1] * acc[1];
            h0.z = up[2] * acc[2]; h0.w = up[3] * acc[3];
            h1.x = up[4] * acc[4]; h1.y = up[5] * acc[5];
            h1.z = up[6] * acc[6]; h1.w = up[7] * acc[7];
            *(float4*)up       = h0;
            *(float4*)(up + 4) = h1;
        }
    }
}

// ---------------------------------------------------------------------------
// K3: out = h @ Wo^T + x*res_scale.  Same tiling as K1. M=MROWS,N=256,K=512.
// ---------------------------------------------------------------------------
__global__ __launch_bounds__(256) void k_gemm2(
    const float* __restrict__ h,     // [MROWS, E]
    const float* __restrict__ Wo,    // [D, E]
    const float* __restrict__ x,     // [MROWS, D]
    const float* __restrict__ resS,  // [D]
    float* __restrict__ out) {       // [MROWS, D]
    __shared__ float As[16][68];
    __shared__ float Bs[16][68];
    const int tid  = threadIdx.x;
    const int row0 = blockIdx.x * 64;
    const int col0 = blockIdx.y * 64;
    const int tx = tid & 15, ty = tid >> 4;
    const int lr = tid >> 2, ls = tid & 3;
    float acc[4][4] = {};
    const float* aptr = h  + (size_t)(row0 + lr) * E_DIM + ls * 4;
    const float* bptr = Wo + (size_t)(col0 + lr) * E_DIM + ls * 4;

    for (int k0 = 0; k0 < E_DIM; k0 += 16) {
        float4 a4 = *(const float4*)(aptr + k0);
        float4 b4 = *(const float4*)(bptr + k0);
        As[ls * 4 + 0][lr] = a4.x;
        As[ls * 4 + 1][lr] = a4.y;
        As[ls * 4 + 2][lr] = a4.z;
        As[ls * 4 + 3][lr] = a4.w;
        Bs[ls * 4 + 0][lr] = b4.x;
        Bs[ls * 4 + 1][lr] = b4.y;
        Bs[ls * 4 + 2][lr] = b4.z;
        Bs[ls * 4 + 3][lr] = b4.w;
        __syncthreads();
#pragma unroll
        for (int kk2 = 0; kk2 < 16; ++kk2) {
            float4 av = *(const float4*)&As[kk2][ty * 4];
            float4 bv = *(const float4*)&Bs[kk2][tx * 4];
            float aa[4] = {av.x, av.y, av.z, av.w};
            float bb[4] = {bv.x, bv.y, bv.z, bv.w};
#pragma unroll
            for (int i = 0; i < 4; ++i)
#pragma unroll
                for (int j = 0; j < 4; ++j)
                    acc[i][j] = fmaf(aa[i], bb[j], acc[i][j]);
        }
        __syncthreads();
    }

#pragma unroll
    for (int i = 0; i < 4; ++i) {
        const size_t r = row0 + ty * 4 + i;
#pragma unroll
        for (int j = 0; j < 4; ++j) {
            const int c = col0 + tx * 4 + j;
            out[r * D_DIM + c] =
                acc[i][j] + x[r * D_DIM + c] * resS[c];
        }
    }
}

// ---------------------------------------------------------------------------
extern "C" void kernel_launch(void* const* d_in, const int* in_sizes, int n_in,
                              void* d_out, int out_size, void* d_ws, size_t ws_size,
                              hipStream_t stream) {
    const float* x     = (const float*)d_in[0];
    const float* Wuv   = (const float*)d_in[1];
    const float* Wo    = (const float*)d_in[2];
    const float* gamma = (const float*)d_in[3];
    const float* beta  = (const float*)d_in[4];
    const float* g     = (const float*)d_in[5];
    const float* resS  = (const float*)d_in[6];
    float* out = (float*)d_out;

    // workspace layout (floats): scale[NTOK] | u | v | q | k   (~44.1 MB)
    float* scale = (float*)d_ws;
    float* u  = scale + NTOK;                    // NTOK divisible by 64
    float* v  = u  + (size_t)MROWS * E_DIM;
    float* q  = v  + (size_t)MROWS * E_DIM;
    float* kk = q  + (size_t)MROWS * S_DIM;

    k_rms<<<NTOK / 4, 256, 0, stream>>>(x, g, scale);

    for (int c = 0; c < B_DIM / CB; ++c) {
        const size_t tok0 = (size_t)c * MROWS;
        k_gemm1<<<dim3(MROWS / 64, N_UV / 64), 256, 0, stream>>>(
            x + tok0 * D_DIM, scale + tok0, Wuv, gamma, beta, u, v, q, kk);
        k_attn<<<dim3(9, CB), 256, 0, stream>>>(q, kk, v, u);
        k_gemm2<<<dim3(MROWS / 64, D_DIM / 64), 256, 0, stream>>>(
            u, Wo, x + tok0 * D_DIM, resS, out + tok0 * D_DIM);
    }
}